// Round 1
// baseline (1294.598 us; speedup 1.0000x reference)
//
#include <hip/hip_runtime.h>
#include <math.h>

#define BB 2
#define NN 512
#define FF 64
#define HH 256
#define LN_EPS 1e-6f

__device__ __forceinline__ float gelu_tanh(float x) {
    // JAX default: approximate=True (tanh form)
    const float c0 = 0.7978845608028654f;
    const float c1 = 0.044715f;
    float u = c0 * (x + c1 * x * x * x);
    return 0.5f * x * (1.0f + tanhf(u));
}

// ---------------- Kernel 1a: Aq = qs@Wa1[0:64]+ba1 ; Ak = ks@Wa1[64:128] ----------------
__global__ __launch_bounds__(256) void precompute_qk_kernel(
    const float* __restrict__ qs, const float* __restrict__ ks,
    const float* __restrict__ Wa1, const float* __restrict__ ba1,
    float* __restrict__ Aq, float* __restrict__ Ak) {
    int idx = blockIdx.x * 256 + threadIdx.x;      // over B*N*H
    int j  = idx & (HH - 1);
    int bn = idx >> 8;
    const float* qrow = qs + bn * FF;
    const float* krow = ks + bn * FF;
    float aq = ba1[j];
    float ak = 0.0f;
#pragma unroll 8
    for (int f = 0; f < FF; ++f) {
        aq += qrow[f] * Wa1[f * HH + j];
        ak += krow[f] * Wa1[(FF + f) * HH + j];
    }
    Aq[idx] = aq;
    Ak[idx] = ak;
}

// ---------------- Kernel 1b: vproj = vs@Wv + bv ----------------
__global__ __launch_bounds__(256) void precompute_v_kernel(
    const float* __restrict__ vs, const float* __restrict__ Wv,
    const float* __restrict__ bv, float* __restrict__ vproj) {
    int idx = blockIdx.x * 256 + threadIdx.x;      // over B*N*64
    int d  = idx & 63;
    int bn = idx >> 6;
    const float* vrow = vs + bn * FF;
    float a = bv[d];
#pragma unroll 8
    for (int f = 0; f < FF; ++f) a += vrow[f] * Wv[f * 64 + d];
    vproj[idx] = a;
}

// ---------------- Kernel 2: per-(b,q) masked pair-MLP + attn@vproj + LN1 ----------------
__global__ __launch_bounds__(256) void attn_ctx_kernel(
    const float* __restrict__ qs_s, const float* __restrict__ ks_s,
    const float* __restrict__ qs_t, const float* __restrict__ ks_t,
    const int*   __restrict__ valid_lens,
    const float* __restrict__ Wa1, const float* __restrict__ Wa2,
    const float* __restrict__ ba2, const float* __restrict__ Wa3,
    const float* __restrict__ ba3,
    const float* __restrict__ Aq,  const float* __restrict__ Ak,
    const float* __restrict__ vproj,
    const float* __restrict__ ln1_s, const float* __restrict__ ln1_b,
    float* __restrict__ ctx_out) {

    __shared__ float s_h1[64 * 257];    // [kl][i] padded stride 257 (writes coalesced, reads bank-spread)
    __shared__ float s_feats[64 * 5];
    __shared__ int   s_kc[64];
    __shared__ float s_part[16 * 68];   // [tj-group][kl]
    __shared__ float s_attn[64];
    __shared__ int   s_klist[512];
    __shared__ int   s_cnt[8];
    __shared__ int   s_off[9];

    const int t  = threadIdx.x;
    const int bq = blockIdx.x;
    const int b  = bq >> 9;
    const int q  = bq & 511;

    const int  vlen    = valid_lens[b];
    const bool q_valid = (q < vlen);
    const float qt  = qs_t[bq];
    const float qss0 = qs_s[bq * 2 + 0];
    const float qss1 = qs_s[bq * 2 + 1];

    // ---- compact valid k indices: mask = q_valid && (qt - kt > 0) ----
    const int lane = t & 63;
    const int w    = t >> 6;
    bool validr[2];
    int  posr[2];
#pragma unroll
    for (int r = 0; r < 2; ++r) {
        int k = r * 256 + t;
        float kt = ks_t[b * NN + k];
        bool valid = q_valid && ((qt - kt) > 0.0f);
        unsigned long long bal = __ballot(valid);
        validr[r] = valid;
        posr[r] = (int)__popcll(bal & ((1ull << lane) - 1ull));
        if (lane == 0) s_cnt[r * 4 + w] = (int)__popcll(bal);
    }
    __syncthreads();
    if (t == 0) {
        int acc = 0;
#pragma unroll
        for (int i = 0; i < 8; ++i) { s_off[i] = acc; acc += s_cnt[i]; }
        s_off[8] = acc;
    }
    __syncthreads();
#pragma unroll
    for (int r = 0; r < 2; ++r)
        if (validr[r]) s_klist[s_off[r * 4 + w] + posr[r]] = r * 256 + t;
    __syncthreads();
    const int nk = s_off[8];

    // ---- hoisted per-thread constants ----
    const int j = t;                               // layer-1 column
    const float aq_j = Aq[bq * HH + j];
    const float wx0 = Wa1[128 * HH + j];
    const float wx1 = Wa1[129 * HH + j];
    const float wx2 = Wa1[130 * HH + j];
    const float wx3 = Wa1[131 * HH + j];
    const float wx4 = Wa1[132 * HH + j];

    const int tj = t & 15;                         // GEMM: column group (16 cols)
    const int tk = t >> 4;                         // GEMM: row group (4 rows)
    float wa3r[16], ba2r[16];
#pragma unroll
    for (int u = 0; u < 16; ++u) {
        wa3r[u] = Wa3[tj * 16 + u];
        ba2r[u] = ba2[tj * 16 + u];
    }
    const float ba3v = ba3[0];

    float ctx_acc = 0.0f;                          // threads 0..63: d = t

    const int nchunks = (nk + 63) >> 6;
    for (int c = 0; c < nchunks; ++c) {
        const int c0 = c << 6;
        const int nv = min(64, nk - c0);

        // ---- step 1: features for up to 64 valid k ----
        if (t < 64) {
            int k;
            if (t < nv) {
                k = s_klist[c0 + t];
                float d0 = qss0 - ks_s[(b * NN + k) * 2 + 0];
                float d1 = qss1 - ks_s[(b * NN + k) * 2 + 1];
                float dist = sqrtf(d0 * d0 + d1 * d1);
                float td = qt - ks_t[b * NN + k];
                s_feats[t * 5 + 0] = d0;
                s_feats[t * 5 + 1] = d1;
                s_feats[t * 5 + 2] = dist;
                s_feats[t * 5 + 3] = dist * dist;
                s_feats[t * 5 + 4] = td;
            } else {
                k = s_klist[c0];                   // safe pad index
#pragma unroll
                for (int i = 0; i < 5; ++i) s_feats[t * 5 + i] = 0.0f;
            }
            s_kc[t] = k;
        }
        __syncthreads();

        // ---- step 2: h1[kl][j] = gelu(Aq + Ak + feats@Wx) ----
#pragma unroll 8
        for (int kl = 0; kl < 64; ++kl) {
            float ak = Ak[(b * NN + s_kc[kl]) * HH + j];
            float v = aq_j + ak
                    + wx0 * s_feats[kl * 5 + 0]
                    + wx1 * s_feats[kl * 5 + 1]
                    + wx2 * s_feats[kl * 5 + 2]
                    + wx3 * s_feats[kl * 5 + 3]
                    + wx4 * s_feats[kl * 5 + 4];
            s_h1[kl * 257 + j] = gelu_tanh(v);
        }
        __syncthreads();

        // ---- step 3: GEMM 64x256 @ 256x256, register tile 4(kl) x 16(j) ----
        float acc[4][16];
#pragma unroll
        for (int r = 0; r < 4; ++r)
#pragma unroll
            for (int u = 0; u < 16; ++u) acc[r][u] = 0.0f;

        const float* hbase = s_h1 + tk * 4 * 257;
#pragma unroll 2
        for (int i = 0; i < HH; ++i) {
            float hv[4];
#pragma unroll
            for (int r = 0; r < 4; ++r) hv[r] = hbase[r * 257 + i];
            const float4* wp = (const float4*)(Wa2 + i * HH + tj * 16);
            float4 w0 = wp[0], w1 = wp[1], w2 = wp[2], w3 = wp[3];
#pragma unroll
            for (int r = 0; r < 4; ++r) {
                acc[r][0]  += hv[r] * w0.x; acc[r][1]  += hv[r] * w0.y;
                acc[r][2]  += hv[r] * w0.z; acc[r][3]  += hv[r] * w0.w;
                acc[r][4]  += hv[r] * w1.x; acc[r][5]  += hv[r] * w1.y;
                acc[r][6]  += hv[r] * w1.z; acc[r][7]  += hv[r] * w1.w;
                acc[r][8]  += hv[r] * w2.x; acc[r][9]  += hv[r] * w2.y;
                acc[r][10] += hv[r] * w2.z; acc[r][11] += hv[r] * w2.w;
                acc[r][12] += hv[r] * w3.x; acc[r][13] += hv[r] * w3.y;
                acc[r][14] += hv[r] * w3.z; acc[r][15] += hv[r] * w3.w;
            }
        }

        // ---- step 4: h2 = gelu(acc+ba2); layer-3 partials ----
#pragma unroll
        for (int r = 0; r < 4; ++r) {
            float p = 0.0f;
#pragma unroll
            for (int u = 0; u < 16; ++u)
                p += gelu_tanh(acc[r][u] + ba2r[u]) * wa3r[u];
            s_part[tj * 68 + tk * 4 + r] = p;
        }
        __syncthreads();

        // ---- attn reduce across 16 tj groups ----
        if (t < 64) {
            float a = 0.0f;
            if (t < nv) {
#pragma unroll
                for (int g = 0; g < 16; ++g) a += s_part[g * 68 + t];
                a += ba3v;
            }
            s_attn[t] = a;
        }
        __syncthreads();

        // ---- ctx accumulate: ctx[d] += sum_kl attn[kl] * vproj[k,d] ----
        if (t < 64) {
#pragma unroll 4
            for (int kl = 0; kl < 64; ++kl)
                ctx_acc += s_attn[kl] * vproj[(b * NN + s_kc[kl]) * 64 + t];
        }
        __syncthreads();   // protect s_h1/s_kc/s_feats for next chunk
    }

    // ---- LN1 over d (threads 0..63 = wave 0) ----
    if (t < 64) {
        float x = ctx_acc;
        float s = x;
#pragma unroll
        for (int m = 1; m < 64; m <<= 1) s += __shfl_xor(s, m);
        float mu = s * (1.0f / 64.0f);
        float dv = x - mu;
        float vv = dv * dv;
#pragma unroll
        for (int m = 1; m < 64; m <<= 1) vv += __shfl_xor(vv, m);
        float var = vv * (1.0f / 64.0f);
        float rs = rsqrtf(var + LN_EPS);
        ctx_out[bq * 64 + t] = dv * rs * ln1_s[t] + ln1_b[t];
    }
}

// ---------------- Kernel 3: gate = gelu(ctx@Wg1+bg1)@Wg2+bg2 ; gctx = masked gate*ctx ----------------
__global__ __launch_bounds__(256) void gate_kernel(
    const float* __restrict__ ctx, const float* __restrict__ Wg1,
    const float* __restrict__ bg1, const float* __restrict__ Wg2,
    const float* __restrict__ bg2, const int* __restrict__ valid_lens,
    float* __restrict__ gctx) {
    __shared__ float s_ctx[64];
    __shared__ float s_hg[256];
    const int t  = threadIdx.x;
    const int bq = blockIdx.x;
    const int b  = bq >> 9;
    const int q  = bq & 511;
    if (t < 64) s_ctx[t] = ctx[bq * 64 + t];
    __syncthreads();
    float a = bg1[t];
#pragma unroll 8
    for (int d = 0; d < 64; ++d) a += s_ctx[d] * Wg1[d * 256 + t];
    s_hg[t] = gelu_tanh(a);
    __syncthreads();
    if (t < 64) {
        float g = bg2[t];
#pragma unroll 8
        for (int jj = 0; jj < 256; ++jj) g += s_hg[jj] * Wg2[jj * 64 + t];
        float val = g * s_ctx[t];
        if (q >= valid_lens[b]) val = -INFINITY;
        gctx[bq * 64 + t] = val;
    }
}

// ---------------- Kernel 4: pooled = max over q ; vnode = LN2(pooled) ----------------
__global__ __launch_bounds__(256) void pool_kernel(
    const float* __restrict__ gctx,
    const float* __restrict__ ln2_s, const float* __restrict__ ln2_b,
    float* __restrict__ vnode_out) {
    __shared__ float s_red[4 * 64];
    const int t = threadIdx.x;
    const int b = blockIdx.x;
    const int d = t & 63;
    const int g = t >> 6;
    float m = -INFINITY;
#pragma unroll 4
    for (int q = g; q < NN; q += 4)
        m = fmaxf(m, gctx[(b * NN + q) * 64 + d]);
    s_red[g * 64 + d] = m;
    __syncthreads();
    if (t < 64) {
        float x = fmaxf(fmaxf(s_red[t], s_red[64 + t]),
                        fmaxf(s_red[128 + t], s_red[192 + t]));
        float s = x;
#pragma unroll
        for (int mm = 1; mm < 64; mm <<= 1) s += __shfl_xor(s, mm);
        float mu = s * (1.0f / 64.0f);
        float dv = x - mu;
        float vv = dv * dv;
#pragma unroll
        for (int mm = 1; mm < 64; mm <<= 1) vv += __shfl_xor(vv, mm);
        float var = vv * (1.0f / 64.0f);
        float rs = rsqrtf(var + LN_EPS);
        vnode_out[b * 64 + t] = dv * rs * ln2_s[t] + ln2_b[t];
    }
}

extern "C" void kernel_launch(void* const* d_in, const int* in_sizes, int n_in,
                              void* d_out, int out_size, void* d_ws, size_t ws_size,
                              hipStream_t stream) {
    const float* qs   = (const float*)d_in[0];
    const float* ks   = (const float*)d_in[1];
    const float* vs   = (const float*)d_in[2];
    const float* qs_s = (const float*)d_in[3];
    const float* ks_s = (const float*)d_in[4];
    const float* qs_t = (const float*)d_in[5];
    const float* ks_t = (const float*)d_in[6];
    const int*   valid_lens = (const int*)d_in[7];
    const float* Wv   = (const float*)d_in[8];
    const float* bv   = (const float*)d_in[9];
    const float* Wa1  = (const float*)d_in[10];
    const float* ba1  = (const float*)d_in[11];
    const float* Wa2  = (const float*)d_in[12];
    const float* ba2  = (const float*)d_in[13];
    const float* Wa3  = (const float*)d_in[14];
    const float* ba3  = (const float*)d_in[15];
    const float* Wg1  = (const float*)d_in[16];
    const float* bg1  = (const float*)d_in[17];
    const float* Wg2  = (const float*)d_in[18];
    const float* bg2  = (const float*)d_in[19];
    const float* ln1_s = (const float*)d_in[20];
    const float* ln1_b = (const float*)d_in[21];
    const float* ln2_s = (const float*)d_in[22];
    const float* ln2_b = (const float*)d_in[23];

    float* out = (float*)d_out;
    float* ws  = (float*)d_ws;
    float* Aq    = ws;                                   // B*N*H
    float* Ak    = ws + BB * NN * HH;                    // B*N*H
    float* vproj = ws + 2 * BB * NN * HH;                // B*N*64
    float* gctx  = vproj + BB * NN * 64;                 // B*N*64

    precompute_qk_kernel<<<(BB * NN * HH) / 256, 256, 0, stream>>>(qs, ks, Wa1, ba1, Aq, Ak);
    precompute_v_kernel<<<(BB * NN * 64) / 256, 256, 0, stream>>>(vs, Wv, bv, vproj);
    attn_ctx_kernel<<<BB * NN, 256, 0, stream>>>(qs_s, ks_s, qs_t, ks_t, valid_lens,
                                                 Wa1, Wa2, ba2, Wa3, ba3,
                                                 Aq, Ak, vproj, ln1_s, ln1_b, out);
    gate_kernel<<<BB * NN, 256, 0, stream>>>(out, Wg1, bg1, Wg2, bg2, valid_lens, gctx);
    pool_kernel<<<BB, 256, 0, stream>>>(gctx, ln2_s, ln2_b, out + BB * NN * 64);
}

// Round 2
// 1232.708 us; speedup vs baseline: 1.0502x; 1.0502x over previous
//
#include <hip/hip_runtime.h>
#include <math.h>

#define BB 2
#define NN 512
#define FF 64
#define HH 256
#define LN_EPS 1e-6f

__device__ __forceinline__ float gelu_tanh(float x) {
    // tanh-form gelu (JAX default), fast tanh via exp
    float u = 0.7978845608028654f * (x + 0.044715f * x * x * x);
    float e = __expf(2.0f * u);
    float th = 1.0f - 2.0f * __builtin_amdgcn_rcpf(e + 1.0f);
    return 0.5f * x * (1.0f + th);
}

__device__ __forceinline__ unsigned short f2bf(float f) {
    unsigned u = __float_as_uint(f);
    unsigned r = u + 0x7fffu + ((u >> 16) & 1u);   // RNE
    return (unsigned short)(r >> 16);
}

// ---------------- Kernel 1a: Aq = qs@Wa1[0:64]+ba1 ; Ak = ks@Wa1[64:128] ----------------
__global__ __launch_bounds__(256) void precompute_qk_kernel(
    const float* __restrict__ qs, const float* __restrict__ ks,
    const float* __restrict__ Wa1, const float* __restrict__ ba1,
    float* __restrict__ Aq, float* __restrict__ Ak) {
    int idx = blockIdx.x * 256 + threadIdx.x;      // over B*N*H
    int j  = idx & (HH - 1);
    int bn = idx >> 8;
    const float* qrow = qs + bn * FF;
    const float* krow = ks + bn * FF;
    float aq = ba1[j];
    float ak = 0.0f;
#pragma unroll 8
    for (int f = 0; f < FF; ++f) {
        aq += qrow[f] * Wa1[f * HH + j];
        ak += krow[f] * Wa1[(FF + f) * HH + j];
    }
    Aq[idx] = aq;
    Ak[idx] = ak;
}

// ---------------- Kernel 1b: vproj = vs@Wv + bv ; zero d_out ctx region ----------------
__global__ __launch_bounds__(256) void precompute_v_kernel(
    const float* __restrict__ vs, const float* __restrict__ Wv,
    const float* __restrict__ bv, float* __restrict__ vproj,
    float* __restrict__ ctx_zero) {
    int idx = blockIdx.x * 256 + threadIdx.x;      // over B*N*64
    int d  = idx & 63;
    int bn = idx >> 6;
    const float* vrow = vs + bn * FF;
    float a = bv[d];
#pragma unroll 8
    for (int f = 0; f < FF; ++f) a += vrow[f] * Wv[f * 64 + d];
    vproj[idx] = a;
    ctx_zero[idx] = 0.0f;                           // ctx accumulator (in d_out)
}

// ---------------- Kernel 2: per-(bq,chunk) slot: masked pair-MLP + attn@vproj ----------------
// grid = B*N*8 slots; each slot handles up to 64 compacted valid k's.
__global__ __launch_bounds__(256, 4) void attn_ctx_kernel(
    const float* __restrict__ ks_s, const float* __restrict__ qs_s,
    const float* __restrict__ qs_t, const float* __restrict__ ks_t,
    const int*   __restrict__ valid_lens,
    const float* __restrict__ Wa1, const float* __restrict__ Wa2,
    const float* __restrict__ ba2, const float* __restrict__ Wa3,
    const float* __restrict__ ba3,
    const float* __restrict__ Aq,  const float* __restrict__ Ak,
    const float* __restrict__ vproj,
    float* __restrict__ ctx_acc_g) {

    __shared__ unsigned short s_h1[256 * 68];  // [j][kl] bf16, stride 68 (8B-aligned rows)
    __shared__ float s_u[16 * 65];             // union: feats (64*5) / layer-3 partials (16x65)
    __shared__ float s_attn[64];
    __shared__ int   s_kc[64];
    __shared__ int   s_cnt[8];
    __shared__ int   s_off[9];

    const int t    = threadIdx.x;
    const int slot = blockIdx.x;
    const int bq   = slot >> 3;
    const int c    = slot & 7;
    const int b    = bq >> 9;
    const int q    = bq & 511;

    const int vlen = valid_lens[b];
    if (q >= vlen) return;                          // uniform exit
    const float qt = qs_t[bq];

    // ---- compaction (recomputed per slot; cheap): mask = (qt - kt) > 0 ----
    const int lane = t & 63;
    const int w    = t >> 6;
    bool validr[2];
    int  posr[2];
#pragma unroll
    for (int r = 0; r < 2; ++r) {
        int k = r * 256 + t;
        float kt = ks_t[b * NN + k];
        bool valid = (qt - kt) > 0.0f;
        unsigned long long bal = __ballot(valid);
        validr[r] = valid;
        posr[r] = (int)__popcll(bal & ((1ull << lane) - 1ull));
        if (lane == 0) s_cnt[r * 4 + w] = (int)__popcll(bal);
    }
    __syncthreads();
    if (t == 0) {
        int acc = 0;
#pragma unroll
        for (int i = 0; i < 8; ++i) { s_off[i] = acc; acc += s_cnt[i]; }
        s_off[8] = acc;
    }
    __syncthreads();
    const int nk = s_off[8];
    const int c0 = c << 6;
    if (c0 >= nk) return;                           // uniform exit (empty slot)

#pragma unroll
    for (int r = 0; r < 2; ++r) {
        if (validr[r]) {
            int gpos = s_off[r * 4 + w] + posr[r];
            if (gpos >= c0 && gpos < c0 + 64) s_kc[gpos - c0] = r * 256 + t;
        }
    }
    __syncthreads();
    const int nv = min(64, nk - c0);

    // ---- step 1: features for this chunk's k's (threads 0..63) ----
    const float qss0 = qs_s[bq * 2 + 0];
    const float qss1 = qs_s[bq * 2 + 1];
    if (t < 64) {
        int k = (t < nv) ? s_kc[t] : s_kc[0];
        s_kc[t] = k;                                // pad slots -> safe index
        if (t < nv) {
            float d0 = qss0 - ks_s[(b * NN + k) * 2 + 0];
            float d1 = qss1 - ks_s[(b * NN + k) * 2 + 1];
            float dist = sqrtf(d0 * d0 + d1 * d1);
            float td = qt - ks_t[b * NN + k];
            s_u[t * 5 + 0] = d0;
            s_u[t * 5 + 1] = d1;
            s_u[t * 5 + 2] = dist;
            s_u[t * 5 + 3] = dist * dist;
            s_u[t * 5 + 4] = td;
        } else {
#pragma unroll
            for (int i = 0; i < 5; ++i) s_u[t * 5 + i] = 0.0f;
        }
    }
    __syncthreads();                                // B1

    // ---- step 2: h1[kl][j] = gelu(Aq + Ak + feats@Wx), stored bf16 [j][kl] ----
    {
        const int j = t;
        const float aq_j = Aq[bq * HH + j];
        const float wx0 = Wa1[128 * HH + j];
        const float wx1 = Wa1[129 * HH + j];
        const float wx2 = Wa1[130 * HH + j];
        const float wx3 = Wa1[131 * HH + j];
        const float wx4 = Wa1[132 * HH + j];
        const float* akbase = Ak + (size_t)b * NN * HH + j;
        unsigned pk = 0;
#pragma unroll 4
        for (int kl = 0; kl < 64; ++kl) {
            int k = s_kc[kl];
            float ak = akbase[(size_t)k * HH];
            const float* ft = s_u + kl * 5;
            float v = aq_j + ak + wx0 * ft[0] + wx1 * ft[1] + wx2 * ft[2]
                    + wx3 * ft[3] + wx4 * ft[4];
            unsigned short h = f2bf(gelu_tanh(v));
            if (kl & 1) {
                ((unsigned*)s_h1)[j * 34 + (kl >> 1)] = pk | ((unsigned)h << 16);
            } else {
                pk = (unsigned)h;
            }
        }
    }
    __syncthreads();                                // B2

    // ---- step 3: GEMM 64x256 @ 256x256, register tile 4(kl) x 16(j) ----
    const int tj = t & 15;                          // column group (16 cols)
    const int tk = t >> 4;                          // row group (4 rows): kl = tk*4+r
    float acc[4][16];
#pragma unroll
    for (int r = 0; r < 4; ++r)
#pragma unroll
        for (int u = 0; u < 16; ++u) acc[r][u] = 0.0f;

#pragma unroll 2
    for (int i = 0; i < HH; ++i) {
        uint2 hb = *(const uint2*)(s_h1 + i * 68 + tk * 4);   // 4 bf16, 8B aligned
        float hv[4];
        hv[0] = __uint_as_float(hb.x << 16);
        hv[1] = __uint_as_float(hb.x & 0xffff0000u);
        hv[2] = __uint_as_float(hb.y << 16);
        hv[3] = __uint_as_float(hb.y & 0xffff0000u);
        const float4* wp = (const float4*)(Wa2 + i * HH + tj * 16);
        float4 w0 = wp[0], w1 = wp[1], w2 = wp[2], w3 = wp[3];
#pragma unroll
        for (int r = 0; r < 4; ++r) {
            acc[r][0]  += hv[r] * w0.x; acc[r][1]  += hv[r] * w0.y;
            acc[r][2]  += hv[r] * w0.z; acc[r][3]  += hv[r] * w0.w;
            acc[r][4]  += hv[r] * w1.x; acc[r][5]  += hv[r] * w1.y;
            acc[r][6]  += hv[r] * w1.z; acc[r][7]  += hv[r] * w1.w;
            acc[r][8]  += hv[r] * w2.x; acc[r][9]  += hv[r] * w2.y;
            acc[r][10] += hv[r] * w2.z; acc[r][11] += hv[r] * w2.w;
            acc[r][12] += hv[r] * w3.x; acc[r][13] += hv[r] * w3.y;
            acc[r][14] += hv[r] * w3.z; acc[r][15] += hv[r] * w3.w;
        }
    }

    // ---- step 4: h2 = gelu(acc+ba2); layer-3 partials into s_u ----
    {
        float p[4] = {0.0f, 0.0f, 0.0f, 0.0f};
#pragma unroll
        for (int u = 0; u < 16; ++u) {
            float bu = ba2[tj * 16 + u];
            float wu = Wa3[tj * 16 + u];
#pragma unroll
            for (int r = 0; r < 4; ++r)
                p[r] += gelu_tanh(acc[r][u] + bu) * wu;
        }
#pragma unroll
        for (int r = 0; r < 4; ++r) s_u[tj * 65 + tk * 4 + r] = p[r];
    }
    __syncthreads();                                // B3

    // ---- step 5: attn reduce across 16 tj groups ----
    if (t < 64) {
        float a = 0.0f;
        if (t < nv) {
#pragma unroll
            for (int g = 0; g < 16; ++g) a += s_u[g * 65 + t];
            a += ba3[0];
        }
        s_attn[t] = a;
    }
    __syncthreads();                                // B4

    // ---- ctx partial: ctx[d] += sum_kl attn[kl] * vproj[k,d] ; atomic merge ----
    if (t < 64) {
        float cacc = 0.0f;
#pragma unroll 4
        for (int kl = 0; kl < 64; ++kl)
            cacc += s_attn[kl] * vproj[(size_t)(b * NN + s_kc[kl]) * 64 + t];
        atomicAdd(&ctx_acc_g[bq * 64 + t], cacc);
    }
}

// ---------------- Kernel 3: LN1 (fused) + gate MLP ; gctx = masked gate*ctx ----------------
__global__ __launch_bounds__(256) void gate_kernel(
    float* __restrict__ ctx,                        // in: raw sums, out: normalized
    const float* __restrict__ ln1_s, const float* __restrict__ ln1_b,
    const float* __restrict__ Wg1, const float* __restrict__ bg1,
    const float* __restrict__ Wg2, const float* __restrict__ bg2,
    const int* __restrict__ valid_lens,
    float* __restrict__ gctx) {
    __shared__ float s_ctx[64];
    __shared__ float s_hg[256];
    const int t  = threadIdx.x;
    const int bq = blockIdx.x;
    const int b  = bq >> 9;
    const int q  = bq & 511;
    if (t < 64) {                                   // wave 0: LN1
        float x = ctx[bq * 64 + t];
        float s = x;
#pragma unroll
        for (int m = 1; m < 64; m <<= 1) s += __shfl_xor(s, m);
        float mu = s * (1.0f / 64.0f);
        float dv = x - mu;
        float vv = dv * dv;
#pragma unroll
        for (int m = 1; m < 64; m <<= 1) vv += __shfl_xor(vv, m);
        float rs = rsqrtf(vv * (1.0f / 64.0f) + LN_EPS);
        float y = dv * rs * ln1_s[t] + ln1_b[t];
        ctx[bq * 64 + t] = y;
        s_ctx[t] = y;
    }
    __syncthreads();
    float a = bg1[t];
#pragma unroll 8
    for (int d = 0; d < 64; ++d) a += s_ctx[d] * Wg1[d * 256 + t];
    s_hg[t] = gelu_tanh(a);
    __syncthreads();
    if (t < 64) {
        float g = bg2[t];
#pragma unroll 8
        for (int jj = 0; jj < 256; ++jj) g += s_hg[jj] * Wg2[jj * 64 + t];
        float val = g * s_ctx[t];
        if (q >= valid_lens[b]) val = -INFINITY;
        gctx[bq * 64 + t] = val;
    }
}

// ---------------- Kernel 4: pooled = max over q ; vnode = LN2(pooled) ----------------
__global__ __launch_bounds__(256) void pool_kernel(
    const float* __restrict__ gctx,
    const float* __restrict__ ln2_s, const float* __restrict__ ln2_b,
    float* __restrict__ vnode_out) {
    __shared__ float s_red[4 * 64];
    const int t = threadIdx.x;
    const int b = blockIdx.x;
    const int d = t & 63;
    const int g = t >> 6;
    float m = -INFINITY;
#pragma unroll 4
    for (int q = g; q < NN; q += 4)
        m = fmaxf(m, gctx[(b * NN + q) * 64 + d]);
    s_red[g * 64 + d] = m;
    __syncthreads();
    if (t < 64) {
        float x = fmaxf(fmaxf(s_red[t], s_red[64 + t]),
                        fmaxf(s_red[128 + t], s_red[192 + t]));
        float s = x;
#pragma unroll
        for (int mm = 1; mm < 64; mm <<= 1) s += __shfl_xor(s, mm);
        float mu = s * (1.0f / 64.0f);
        float dv = x - mu;
        float vv = dv * dv;
#pragma unroll
        for (int mm = 1; mm < 64; mm <<= 1) vv += __shfl_xor(vv, mm);
        float rs = rsqrtf(vv * (1.0f / 64.0f) + LN_EPS);
        vnode_out[b * 64 + t] = dv * rs * ln2_s[t] + ln2_b[t];
    }
}

extern "C" void kernel_launch(void* const* d_in, const int* in_sizes, int n_in,
                              void* d_out, int out_size, void* d_ws, size_t ws_size,
                              hipStream_t stream) {
    const float* qs   = (const float*)d_in[0];
    const float* ks   = (const float*)d_in[1];
    const float* vs   = (const float*)d_in[2];
    const float* qs_s = (const float*)d_in[3];
    const float* ks_s = (const float*)d_in[4];
    const float* qs_t = (const float*)d_in[5];
    const float* ks_t = (const float*)d_in[6];
    const int*   valid_lens = (const int*)d_in[7];
    const float* Wv   = (const float*)d_in[8];
    const float* bv   = (const float*)d_in[9];
    const float* Wa1  = (const float*)d_in[10];
    const float* ba1  = (const float*)d_in[11];
    const float* Wa2  = (const float*)d_in[12];
    const float* ba2  = (const float*)d_in[13];
    const float* Wa3  = (const float*)d_in[14];
    const float* ba3  = (const float*)d_in[15];
    const float* Wg1  = (const float*)d_in[16];
    const float* bg1  = (const float*)d_in[17];
    const float* Wg2  = (const float*)d_in[18];
    const float* bg2  = (const float*)d_in[19];
    const float* ln1_s = (const float*)d_in[20];
    const float* ln1_b = (const float*)d_in[21];
    const float* ln2_s = (const float*)d_in[22];
    const float* ln2_b = (const float*)d_in[23];

    float* out = (float*)d_out;                     // [0,65536): ctx ; [65536,65664): vnode
    float* ws  = (float*)d_ws;
    float* Aq    = ws;                              // B*N*H
    float* Ak    = ws + BB * NN * HH;               // B*N*H
    float* vproj = ws + 2 * BB * NN * HH;           // B*N*64
    float* gctx  = vproj + BB * NN * 64;            // B*N*64

    precompute_qk_kernel<<<(BB * NN * HH) / 256, 256, 0, stream>>>(qs, ks, Wa1, ba1, Aq, Ak);
    precompute_v_kernel<<<(BB * NN * 64) / 256, 256, 0, stream>>>(vs, Wv, bv, vproj, out);
    attn_ctx_kernel<<<BB * NN * 8, 256, 0, stream>>>(ks_s, qs_s, qs_t, ks_t, valid_lens,
                                                     Wa1, Wa2, ba2, Wa3, ba3,
                                                     Aq, Ak, vproj, out);
    gate_kernel<<<BB * NN, 256, 0, stream>>>(out, ln1_s, ln1_b, Wg1, bg1, Wg2, bg2,
                                             valid_lens, gctx);
    pool_kernel<<<BB, 256, 0, stream>>>(gctx, ln2_s, ln2_b, out + BB * NN * 64);
}

// Round 3
// 283.189 us; speedup vs baseline: 4.5715x; 4.3530x over previous
//
#include <hip/hip_runtime.h>
#include <math.h>

#define BB 2
#define NN 512
#define FF 64
#define HH 256
#define LN_EPS 1e-6f

typedef __attribute__((ext_vector_type(8))) short short8v;   // 8 bf16 (4 VGPRs)
typedef __attribute__((ext_vector_type(4))) float float4v;   // 4 fp32 acc

#define LDAH 264   // s_h1 leading dim in bf16 elems (528B: 16B-aligned, 4-bank row rotation)

__device__ __forceinline__ float gelu_tanh(float x) {
    // tanh-form gelu (JAX default), fast tanh via exp
    float u = 0.7978845608028654f * (x + 0.044715f * x * x * x);
    float e = __expf(2.0f * u);
    float th = 1.0f - 2.0f * __builtin_amdgcn_rcpf(e + 1.0f);
    return 0.5f * x * (1.0f + th);
}

__device__ __forceinline__ unsigned short f2bf(float f) {
    unsigned u = __float_as_uint(f);
    unsigned r = u + 0x7fffu + ((u >> 16) & 1u);   // RNE
    return (unsigned short)(r >> 16);
}

// ---------------- Kernel 1a: Aq = qs@Wa1[0:64]+ba1 ; Ak = ks@Wa1[64:128] ----------------
__global__ __launch_bounds__(256) void precompute_qk_kernel(
    const float* __restrict__ qs, const float* __restrict__ ks,
    const float* __restrict__ Wa1, const float* __restrict__ ba1,
    float* __restrict__ Aq, float* __restrict__ Ak) {
    int idx = blockIdx.x * 256 + threadIdx.x;      // over B*N*H
    int j  = idx & (HH - 1);
    int bn = idx >> 8;
    const float* qrow = qs + bn * FF;
    const float* krow = ks + bn * FF;
    float aq = ba1[j];
    float ak = 0.0f;
#pragma unroll 8
    for (int f = 0; f < FF; ++f) {
        aq += qrow[f] * Wa1[f * HH + j];
        ak += krow[f] * Wa1[(FF + f) * HH + j];
    }
    Aq[idx] = aq;
    Ak[idx] = ak;
}

// ---------------- Kernel 1b: vproj = vs@Wv + bv ; zero d_out ctx region ----------------
__global__ __launch_bounds__(256) void precompute_v_kernel(
    const float* __restrict__ vs, const float* __restrict__ Wv,
    const float* __restrict__ bv, float* __restrict__ vproj,
    float* __restrict__ ctx_zero) {
    int idx = blockIdx.x * 256 + threadIdx.x;      // over B*N*64
    int d  = idx & 63;
    int bn = idx >> 6;
    const float* vrow = vs + bn * FF;
    float a = bv[d];
#pragma unroll 8
    for (int f = 0; f < FF; ++f) a += vrow[f] * Wv[f * 64 + d];
    vproj[idx] = a;
    ctx_zero[idx] = 0.0f;                           // ctx accumulator (in d_out)
}

// ---------------- Kernel 1c: Wa2T bf16 [j2][i] <- Wa2 fp32 [i][j2] ----------------
__global__ __launch_bounds__(256) void wa2t_kernel(
    const float* __restrict__ Wa2, unsigned short* __restrict__ Wa2T) {
    int idx = blockIdx.x * 256 + threadIdx.x;      // over 256*256; idx = n*256+i
    int n = idx >> 8;
    int i = idx & 255;
    Wa2T[idx] = f2bf(Wa2[i * HH + n]);
}

// ---------------- Kernel 2: per-(bq,chunk) slot: masked pair-MLP (MFMA) + attn@vproj ----------------
// grid = B*N*8 slots; each slot handles up to 64 compacted valid k's.
__global__ __launch_bounds__(256, 3) void attn_ctx_kernel(
    const float* __restrict__ ks_s, const float* __restrict__ qs_s,
    const float* __restrict__ qs_t, const float* __restrict__ ks_t,
    const int*   __restrict__ valid_lens,
    const float* __restrict__ Wa1,
    const unsigned short* __restrict__ Wa2T,
    const float* __restrict__ ba2, const float* __restrict__ Wa3,
    const float* __restrict__ ba3,
    const float* __restrict__ Aq,  const float* __restrict__ Ak,
    const float* __restrict__ vproj,
    float* __restrict__ ctx_acc_g) {

    __shared__ unsigned short s_h1[64 * LDAH];     // [kl][i] bf16, 33792 B
    __shared__ float4 s_feat4[64];                 // {d0, d1, dist, td}
    __shared__ int    s_koff[64];                  // (b*NN+k)*64
    __shared__ float  s_part[4 * 64];              // per-wave attn row partials
    __shared__ float  s_attn[64];
    __shared__ int    s_kc[64];
    __shared__ int    s_cnt[8];
    __shared__ int    s_off[9];

    const int t    = threadIdx.x;
    const int slot = blockIdx.x;
    const int bq   = slot >> 3;
    const int c    = slot & 7;
    const int b    = bq >> 9;
    const int q    = bq & 511;

    const int vlen = valid_lens[b];
    if (q >= vlen) return;                          // uniform exit
    const float qt = qs_t[bq];

    // ---- compaction (recomputed per slot; cheap): mask = (qt - kt) > 0 ----
    const int lane = t & 63;
    const int w    = t >> 6;
    bool validr[2];
    int  posr[2];
#pragma unroll
    for (int r = 0; r < 2; ++r) {
        int k = r * 256 + t;
        float kt = ks_t[b * NN + k];
        bool valid = (qt - kt) > 0.0f;
        unsigned long long bal = __ballot(valid);
        validr[r] = valid;
        posr[r] = (int)__popcll(bal & ((1ull << lane) - 1ull));
        if (lane == 0) s_cnt[r * 4 + w] = (int)__popcll(bal);
    }
    __syncthreads();
    if (t == 0) {
        int acc = 0;
#pragma unroll
        for (int i = 0; i < 8; ++i) { s_off[i] = acc; acc += s_cnt[i]; }
        s_off[8] = acc;
    }
    __syncthreads();
    const int nk = s_off[8];
    const int c0 = c << 6;
    if (c0 >= nk) return;                           // uniform exit (empty slot)

#pragma unroll
    for (int r = 0; r < 2; ++r) {
        if (validr[r]) {
            int gpos = s_off[r * 4 + w] + posr[r];
            if (gpos >= c0 && gpos < c0 + 64) s_kc[gpos - c0] = r * 256 + t;
        }
    }
    __syncthreads();
    const int nv = min(64, nk - c0);

    // ---- step 1: features + gather offsets for this chunk (threads 0..63) ----
    const float qss0 = qs_s[bq * 2 + 0];
    const float qss1 = qs_s[bq * 2 + 1];
    if (t < 64) {
        int k = (t < nv) ? s_kc[t] : s_kc[0];       // pad -> safe real index
        float d0 = qss0 - ks_s[(b * NN + k) * 2 + 0];
        float d1 = qss1 - ks_s[(b * NN + k) * 2 + 1];
        float dist = sqrtf(d0 * d0 + d1 * d1);
        float td = qt - ks_t[b * NN + k];
        s_feat4[t] = make_float4(d0, d1, dist, td);
        s_koff[t]  = (b * NN + k) * 64;
    }
    __syncthreads();                                // B1

    // ---- step 2: h1[kl][j] = gelu(Aq + Ak + feats@Wx) -> bf16 LDS [kl][i] ----
    {
        const int j = t;
        const float aq_j = Aq[bq * HH + j];
        const float wx0 = Wa1[128 * HH + j];
        const float wx1 = Wa1[129 * HH + j];
        const float wx2 = Wa1[130 * HH + j];
        const float wx3 = Wa1[131 * HH + j];
        const float wx4 = Wa1[132 * HH + j];
#pragma unroll 4
        for (int kl = 0; kl < 64; ++kl) {
            int koff = s_koff[kl];                  // broadcast
            float4 f = s_feat4[kl];                 // broadcast b128
            float ak = Ak[(size_t)koff * 4 + j];    // coalesced 256B/wave
            float v = aq_j + ak + wx0 * f.x + wx1 * f.y + wx2 * f.z
                    + wx3 * (f.z * f.z) + wx4 * f.w;
            s_h1[kl * LDAH + j] = f2bf(gelu_tanh(v));
        }
    }
    __syncthreads();                                // B2

    // ---- step 3: MFMA GEMM 64x256 @ (256x256)^T-loaded; wave w owns cols n0..n0+63 ----
    const int n0   = w * 64;
    const int l15  = lane & 15;
    const int quad = lane >> 4;

    float4v acc[4][4];                              // [mt][nt], rows mt*16+quad*4+r, col n0+nt*16+l15
#pragma unroll
    for (int mt = 0; mt < 4; ++mt)
#pragma unroll
        for (int nt = 0; nt < 4; ++nt) acc[mt][nt] = (float4v){0.f, 0.f, 0.f, 0.f};

    const unsigned short* abase = s_h1 + l15 * LDAH + quad * 8;
    const unsigned short* bbase = Wa2T + (size_t)(n0 + l15) * HH + quad * 8;

#pragma unroll 2
    for (int ks = 0; ks < 8; ++ks) {
        const int k0 = ks * 32;
        short8v Bf[4], Af[4];
#pragma unroll
        for (int nt = 0; nt < 4; ++nt)
            Bf[nt] = *(const short8v*)(bbase + (size_t)nt * 16 * HH + k0);
#pragma unroll
        for (int mt = 0; mt < 4; ++mt)
            Af[mt] = *(const short8v*)(abase + mt * 16 * LDAH + k0);
#pragma unroll
        for (int mt = 0; mt < 4; ++mt)
#pragma unroll
            for (int nt = 0; nt < 4; ++nt)
                acc[mt][nt] = __builtin_amdgcn_mfma_f32_16x16x32_bf16(
                    Af[mt], Bf[nt], acc[mt][nt], 0, 0, 0);
    }

    // ---- step 4: epilogue — h2 = gelu(acc + ba2), dot Wa3, reduce rows ----
    {
        float ba2r[4], wa3r[4];
#pragma unroll
        for (int nt = 0; nt < 4; ++nt) {
            int col = n0 + nt * 16 + l15;
            ba2r[nt] = ba2[col];
            wa3r[nt] = Wa3[col];
        }
        float prow[4][4];                           // [mt][r]
#pragma unroll
        for (int mt = 0; mt < 4; ++mt)
#pragma unroll
            for (int r = 0; r < 4; ++r) prow[mt][r] = 0.0f;
#pragma unroll
        for (int mt = 0; mt < 4; ++mt)
#pragma unroll
            for (int nt = 0; nt < 4; ++nt)
#pragma unroll
                for (int r = 0; r < 4; ++r)
                    prow[mt][r] += gelu_tanh(acc[mt][nt][r] + ba2r[nt]) * wa3r[nt];
        // reduce over the 16 lanes of each quad (same rows, different cols)
#pragma unroll
        for (int m = 1; m < 16; m <<= 1)
#pragma unroll
            for (int mt = 0; mt < 4; ++mt)
#pragma unroll
                for (int r = 0; r < 4; ++r)
                    prow[mt][r] += __shfl_xor(prow[mt][r], m);
        if (l15 == 0) {
#pragma unroll
            for (int mt = 0; mt < 4; ++mt)
#pragma unroll
                for (int r = 0; r < 4; ++r)
                    s_part[w * 64 + mt * 16 + quad * 4 + r] = prow[mt][r];
        }
    }
    __syncthreads();                                // B3

    // ---- step 5: attn = sum of 4 wave partials + ba3 (zero pad rows) ----
    if (t < 64) {
        float a = 0.0f;
        if (t < nv)
            a = s_part[t] + s_part[64 + t] + s_part[128 + t] + s_part[192 + t] + ba3[0];
        s_attn[t] = a;
    }
    __syncthreads();                                // B4

    // ---- ctx partial: ctx[d] += sum_kl attn[kl] * vproj[k,d] ; atomic merge ----
    if (t < 64) {
        float cacc = 0.0f;
#pragma unroll 4
        for (int kl = 0; kl < 64; ++kl)
            cacc += s_attn[kl] * vproj[(size_t)s_koff[kl] + t];
        atomicAdd(&ctx_acc_g[bq * 64 + t], cacc);
    }
}

// ---------------- Kernel 3: LN1 (fused) + gate MLP ; gctx = masked gate*ctx ----------------
__global__ __launch_bounds__(256) void gate_kernel(
    float* __restrict__ ctx,                        // in: raw sums, out: normalized
    const float* __restrict__ ln1_s, const float* __restrict__ ln1_b,
    const float* __restrict__ Wg1, const float* __restrict__ bg1,
    const float* __restrict__ Wg2, const float* __restrict__ bg2,
    const int* __restrict__ valid_lens,
    float* __restrict__ gctx) {
    __shared__ float s_ctx[64];
    __shared__ float s_hg[256];
    const int t  = threadIdx.x;
    const int bq = blockIdx.x;
    const int b  = bq >> 9;
    const int q  = bq & 511;
    if (t < 64) {                                   // wave 0: LN1
        float x = ctx[bq * 64 + t];
        float s = x;
#pragma unroll
        for (int m = 1; m < 64; m <<= 1) s += __shfl_xor(s, m);
        float mu = s * (1.0f / 64.0f);
        float dv = x - mu;
        float vv = dv * dv;
#pragma unroll
        for (int m = 1; m < 64; m <<= 1) vv += __shfl_xor(vv, m);
        float rs = rsqrtf(vv * (1.0f / 64.0f) + LN_EPS);
        float y = dv * rs * ln1_s[t] + ln1_b[t];
        ctx[bq * 64 + t] = y;
        s_ctx[t] = y;
    }
    __syncthreads();
    float a = bg1[t];
#pragma unroll 8
    for (int d = 0; d < 64; ++d) a += s_ctx[d] * Wg1[d * 256 + t];
    s_hg[t] = gelu_tanh(a);
    __syncthreads();
    if (t < 64) {
        float g = bg2[t];
#pragma unroll 8
        for (int jj = 0; jj < 256; ++jj) g += s_hg[jj] * Wg2[jj * 64 + t];
        float val = g * s_ctx[t];
        if (q >= valid_lens[b]) val = -INFINITY;
        gctx[bq * 64 + t] = val;
    }
}

// ---------------- Kernel 4: pooled = max over q ; vnode = LN2(pooled) ----------------
__global__ __launch_bounds__(256) void pool_kernel(
    const float* __restrict__ gctx,
    const float* __restrict__ ln2_s, const float* __restrict__ ln2_b,
    float* __restrict__ vnode_out) {
    __shared__ float s_red[4 * 64];
    const int t = threadIdx.x;
    const int b = blockIdx.x;
    const int d = t & 63;
    const int g = t >> 6;
    float m = -INFINITY;
#pragma unroll 4
    for (int q = g; q < NN; q += 4)
        m = fmaxf(m, gctx[(b * NN + q) * 64 + d]);
    s_red[g * 64 + d] = m;
    __syncthreads();
    if (t < 64) {
        float x = fmaxf(fmaxf(s_red[t], s_red[64 + t]),
                        fmaxf(s_red[128 + t], s_red[192 + t]));
        float s = x;
#pragma unroll
        for (int mm = 1; mm < 64; mm <<= 1) s += __shfl_xor(s, mm);
        float mu = s * (1.0f / 64.0f);
        float dv = x - mu;
        float vv = dv * dv;
#pragma unroll
        for (int mm = 1; mm < 64; mm <<= 1) vv += __shfl_xor(vv, mm);
        float rs = rsqrtf(vv * (1.0f / 64.0f) + LN_EPS);
        vnode_out[b * 64 + t] = dv * rs * ln2_s[t] + ln2_b[t];
    }
}

extern "C" void kernel_launch(void* const* d_in, const int* in_sizes, int n_in,
                              void* d_out, int out_size, void* d_ws, size_t ws_size,
                              hipStream_t stream) {
    const float* qs   = (const float*)d_in[0];
    const float* ks   = (const float*)d_in[1];
    const float* vs   = (const float*)d_in[2];
    const float* qs_s = (const float*)d_in[3];
    const float* ks_s = (const float*)d_in[4];
    const float* qs_t = (const float*)d_in[5];
    const float* ks_t = (const float*)d_in[6];
    const int*   valid_lens = (const int*)d_in[7];
    const float* Wv   = (const float*)d_in[8];
    const float* bv   = (const float*)d_in[9];
    const float* Wa1  = (const float*)d_in[10];
    const float* ba1  = (const float*)d_in[11];
    const float* Wa2  = (const float*)d_in[12];
    const float* ba2  = (const float*)d_in[13];
    const float* Wa3  = (const float*)d_in[14];
    const float* ba3  = (const float*)d_in[15];
    const float* Wg1  = (const float*)d_in[16];
    const float* bg1  = (const float*)d_in[17];
    const float* Wg2  = (const float*)d_in[18];
    const float* bg2  = (const float*)d_in[19];
    const float* ln1_s = (const float*)d_in[20];
    const float* ln1_b = (const float*)d_in[21];
    const float* ln2_s = (const float*)d_in[22];
    const float* ln2_b = (const float*)d_in[23];

    float* out = (float*)d_out;                     // [0,65536): ctx ; [65536,65664): vnode
    float* ws  = (float*)d_ws;
    float* Aq    = ws;                              // B*N*H           = 262144 f
    float* Ak    = Aq + BB * NN * HH;               // B*N*H           = 262144 f
    float* vproj = Ak + BB * NN * HH;               // B*N*64          =  65536 f
    float* gctx  = vproj + BB * NN * 64;            // B*N*64          =  65536 f
    unsigned short* Wa2T = (unsigned short*)(gctx + BB * NN * 64);   // 256*256 bf16 = 128KB

    precompute_qk_kernel<<<(BB * NN * HH) / 256, 256, 0, stream>>>(qs, ks, Wa1, ba1, Aq, Ak);
    precompute_v_kernel<<<(BB * NN * 64) / 256, 256, 0, stream>>>(vs, Wv, bv, vproj, out);
    wa2t_kernel<<<(HH * HH) / 256, 256, 0, stream>>>(Wa2, Wa2T);
    attn_ctx_kernel<<<BB * NN * 8, 256, 0, stream>>>(ks_s, qs_s, qs_t, ks_t, valid_lens,
                                                     Wa1, Wa2T, ba2, Wa3, ba3,
                                                     Aq, Ak, vproj, out);
    gate_kernel<<<BB * NN, 256, 0, stream>>>(out, ln1_s, ln1_b, Wg1, bg1, Wg2, bg2,
                                             valid_lens, gctx);
    pool_kernel<<<BB, 256, 0, stream>>>(gctx, ln2_s, ln2_b, out + BB * NN * 64);
}

// Round 4
// 266.084 us; speedup vs baseline: 4.8654x; 1.0643x over previous
//
#include <hip/hip_runtime.h>
#include <math.h>

#define BB 2
#define NN 512
#define FF 64
#define HH 256
#define LN_EPS 1e-6f

typedef __attribute__((ext_vector_type(8))) short short8v;   // 8 bf16 (4 VGPRs)
typedef __attribute__((ext_vector_type(4))) float float4v;   // 4 fp32 acc

#define LDAH 264   // s_h1 leading dim in bf16 elems (528B: 16B-aligned, even 8-phase bank spread)

__device__ __forceinline__ float gelu_tanh(float x) {
    // 0.5x(1+tanh(c0(x+c1 x^3))) == x - x*rcp(1 + e^{2u})
    float x2 = x * x;
    float t1 = __builtin_fmaf(0.044715f, x2, 1.0f);
    float u2 = x * (1.5957691216057308f) * t1;      // 2*c0*x*(1+c1*x^2)
    float e  = __expf(u2);                          // e^{2u}
    float r  = __builtin_amdgcn_rcpf(e + 1.0f);
    return x - x * r;
}

__device__ __forceinline__ unsigned short f2bf(float f) {
    unsigned u = __float_as_uint(f);
    unsigned r = u + 0x7fffu + ((u >> 16) & 1u);   // RNE
    return (unsigned short)(r >> 16);
}

// ---------------- Kernel 1: merged prep ----------------
// blocks [0,1024): Aq/Ak ; [1024,1280): vproj + ctx zero ; [1280,1536): Wa2T bf16 transpose
__global__ __launch_bounds__(256) void prep_kernel(
    const float* __restrict__ qs, const float* __restrict__ ks,
    const float* __restrict__ vs,
    const float* __restrict__ Wa1, const float* __restrict__ ba1,
    const float* __restrict__ Wv,  const float* __restrict__ bv,
    const float* __restrict__ Wa2,
    float* __restrict__ Aq, float* __restrict__ Ak,
    float* __restrict__ vproj, unsigned short* __restrict__ Wa2T,
    float* __restrict__ ctx_zero) {
    const int bid = blockIdx.x;
    const int t   = threadIdx.x;
    if (bid < 1024) {
        int idx = bid * 256 + t;                   // over B*N*H
        int j  = idx & (HH - 1);
        int bn = idx >> 8;
        const float* qrow = qs + bn * FF;
        const float* krow = ks + bn * FF;
        float aq = ba1[j];
        float ak = 0.0f;
#pragma unroll 8
        for (int f = 0; f < FF; ++f) {
            aq += qrow[f] * Wa1[f * HH + j];
            ak += krow[f] * Wa1[(FF + f) * HH + j];
        }
        Aq[idx] = aq;
        Ak[idx] = ak;
    } else if (bid < 1280) {
        int idx = (bid - 1024) * 256 + t;          // over B*N*64
        int d  = idx & 63;
        int bn = idx >> 6;
        const float* vrow = vs + bn * FF;
        float a = bv[d];
#pragma unroll 8
        for (int f = 0; f < FF; ++f) a += vrow[f] * Wv[f * 64 + d];
        vproj[idx] = a;
        ctx_zero[idx] = 0.0f;
    } else {
        int idx = (bid - 1280) * 256 + t;          // idx = n*256 + i
        int n = idx >> 8;
        int i = idx & 255;
        Wa2T[idx] = f2bf(Wa2[i * HH + n]);
    }
}

// ---------------- Kernel 2: per-(bq,chunk) slot: masked pair-MLP (MFMA) + attn@vproj ----------------
__global__ __launch_bounds__(256, 3) void attn_ctx_kernel(
    const float* __restrict__ ks_s, const float* __restrict__ qs_s,
    const float* __restrict__ qs_t, const float* __restrict__ ks_t,
    const int*   __restrict__ valid_lens,
    const float* __restrict__ Wa1,
    const unsigned short* __restrict__ Wa2T,
    const float* __restrict__ ba2, const float* __restrict__ Wa3,
    const float* __restrict__ ba3,
    const float* __restrict__ Aq,  const float* __restrict__ Ak,
    const float* __restrict__ vproj,
    float* __restrict__ ctx_acc_g) {

    __shared__ unsigned short s_h1[64 * LDAH];     // [kl][i] bf16, 33792 B
    __shared__ float4 s_feat4[64];                 // {d0, d1, dist, td}
    __shared__ int    s_koe[64];                   // (b*NN+k)*HH  (Ak elem offset)
    __shared__ int    s_kvo[64];                   // (b*NN+k)*64  (vproj elem offset)
    __shared__ float  s_part[4 * 64];              // per-wave attn row partials
    __shared__ float  s_attn[64];
    __shared__ int    s_kc[64];
    __shared__ int    s_cnt[8];
    __shared__ int    s_off[9];

    const int t    = threadIdx.x;
    const int slot = blockIdx.x;
    const int bq   = slot >> 3;
    const int c    = slot & 7;
    const int b    = bq >> 9;
    const int q    = bq & 511;

    const int vlen = valid_lens[b];
    if (q >= vlen) return;                          // uniform exit
    const float qt = qs_t[bq];

    const int lane = t & 63;
    const int w    = t >> 6;

    // ---- compaction: mask = (qt - kt) > 0 ----
    bool validr[2];
    int  posr[2];
#pragma unroll
    for (int r = 0; r < 2; ++r) {
        int k = r * 256 + t;
        float kt = ks_t[b * NN + k];
        bool valid = (qt - kt) > 0.0f;
        unsigned long long bal = __ballot(valid);
        validr[r] = valid;
        posr[r] = (int)__popcll(bal & ((1ull << lane) - 1ull));
        if (lane == 0) s_cnt[r * 4 + w] = (int)__popcll(bal);
    }
    __syncthreads();
    if (t == 0) {
        int acc = 0;
#pragma unroll
        for (int i = 0; i < 8; ++i) { s_off[i] = acc; acc += s_cnt[i]; }
        s_off[8] = acc;
    }
    __syncthreads();
    const int nk = s_off[8];
    const int c0 = c << 6;
    if (c0 >= nk) return;                           // uniform exit (empty slot)

    // ---- pre-issue B-fragments for ks=0 (drain under compaction + h1 phase) ----
    const int n0   = w * 64;
    const int l15  = lane & 15;
    const int quad = lane >> 4;
    const unsigned short* bbase = Wa2T + (size_t)(n0 + l15) * HH + quad * 8;
    short8v Bcur[4];
#pragma unroll
    for (int nt = 0; nt < 4; ++nt)
        Bcur[nt] = *(const short8v*)(bbase + (size_t)nt * 16 * HH);

#pragma unroll
    for (int r = 0; r < 2; ++r) {
        if (validr[r]) {
            int gpos = s_off[r * 4 + w] + posr[r];
            if (gpos >= c0 && gpos < c0 + 64) s_kc[gpos - c0] = r * 256 + t;
        }
    }
    __syncthreads();
    const int nv = min(64, nk - c0);

    // ---- step 1: features + offsets for this chunk (threads 0..63) ----
    const float qss0 = qs_s[bq * 2 + 0];
    const float qss1 = qs_s[bq * 2 + 1];
    if (t < 64) {
        int k = (t < nv) ? s_kc[t] : s_kc[0];       // pad -> safe real index
        int bk = b * NN + k;
        float d0 = qss0 - ks_s[bk * 2 + 0];
        float d1 = qss1 - ks_s[bk * 2 + 1];
        float dist = sqrtf(d0 * d0 + d1 * d1);
        float td = qt - ks_t[bk];
        s_feat4[t] = make_float4(d0, d1, dist, td);
        s_koe[t] = bk * HH;
        s_kvo[t] = bk * 64;
    }
    __syncthreads();                                // B1

    // ---- step 2: h1[kl][j] = gelu(Aq + Ak + feats@Wx) -> bf16 LDS [kl][j] ----
    {
        const int j = t;
        const float aq_j = Aq[bq * HH + j];
        const float wx0 = Wa1[128 * HH + j];
        const float wx1 = Wa1[129 * HH + j];
        const float wx2 = Wa1[130 * HH + j];
        const float wx3 = Wa1[131 * HH + j];
        const float wx4 = Wa1[132 * HH + j];
        const float* __restrict__ Akj = Ak + j;
#pragma unroll
        for (int g = 0; g < 8; ++g) {
            float akv[8];
#pragma unroll
            for (int u = 0; u < 8; ++u)             // 8 independent gathers in flight
                akv[u] = Akj[s_koe[g * 8 + u]];
#pragma unroll
            for (int u = 0; u < 8; ++u) {
                int kl = g * 8 + u;
                float4 f = s_feat4[kl];
                float v = aq_j + akv[u] + wx0 * f.x + wx1 * f.y + wx2 * f.z
                        + wx3 * (f.z * f.z) + wx4 * f.w;
                s_h1[kl * LDAH + j] = f2bf(gelu_tanh(v));
            }
        }
    }
    __syncthreads();                                // B2

    // ---- step 3: MFMA GEMM 64x256 @ Wa2T; wave w owns cols n0..n0+63; rolling B prefetch ----
    float4v acc[4][4];
#pragma unroll
    for (int mt = 0; mt < 4; ++mt)
#pragma unroll
        for (int nt = 0; nt < 4; ++nt) acc[mt][nt] = (float4v){0.f, 0.f, 0.f, 0.f};

    const unsigned short* abase = s_h1 + l15 * LDAH + quad * 8;

#pragma unroll
    for (int ksx = 0; ksx < 8; ++ksx) {
        short8v Bnxt[4];
        if (ksx < 7) {
            const int k1 = (ksx + 1) * 32;
#pragma unroll
            for (int nt = 0; nt < 4; ++nt)
                Bnxt[nt] = *(const short8v*)(bbase + (size_t)nt * 16 * HH + k1);
        }
        short8v Af[4];
        const int k0 = ksx * 32;
#pragma unroll
        for (int mt = 0; mt < 4; ++mt)
            Af[mt] = *(const short8v*)(abase + mt * 16 * LDAH + k0);
#pragma unroll
        for (int mt = 0; mt < 4; ++mt)
#pragma unroll
            for (int nt = 0; nt < 4; ++nt)
                acc[mt][nt] = __builtin_amdgcn_mfma_f32_16x16x32_bf16(
                    Af[mt], Bcur[nt], acc[mt][nt], 0, 0, 0);
        if (ksx < 7) {
#pragma unroll
            for (int nt = 0; nt < 4; ++nt) Bcur[nt] = Bnxt[nt];
        }
    }

    // ---- step 4: epilogue — h2 = gelu(acc + ba2), dot Wa3, reduce over 16 cols/quad ----
    {
        float ba2r[4], wa3r[4];
#pragma unroll
        for (int nt = 0; nt < 4; ++nt) {
            int col = n0 + nt * 16 + l15;
            ba2r[nt] = ba2[col];
            wa3r[nt] = Wa3[col];
        }
        float prow[4][4];                           // [mt][r]
#pragma unroll
        for (int mt = 0; mt < 4; ++mt)
#pragma unroll
            for (int r = 0; r < 4; ++r) prow[mt][r] = 0.0f;
#pragma unroll
        for (int mt = 0; mt < 4; ++mt)
#pragma unroll
            for (int nt = 0; nt < 4; ++nt)
#pragma unroll
                for (int r = 0; r < 4; ++r)
                    prow[mt][r] += gelu_tanh(acc[mt][nt][r] + ba2r[nt]) * wa3r[nt];
#pragma unroll
        for (int m = 1; m < 16; m <<= 1)
#pragma unroll
            for (int mt = 0; mt < 4; ++mt)
#pragma unroll
                for (int r = 0; r < 4; ++r)
                    prow[mt][r] += __shfl_xor(prow[mt][r], m);
        if (l15 == 0) {
#pragma unroll
            for (int mt = 0; mt < 4; ++mt)
#pragma unroll
                for (int r = 0; r < 4; ++r)
                    s_part[w * 64 + mt * 16 + quad * 4 + r] = prow[mt][r];
        }
    }
    __syncthreads();                                // B3

    // ---- step 5: attn = sum of 4 wave partials + ba3 (zero pad rows) ----
    if (t < 64) {
        float a = 0.0f;
        if (t < nv)
            a = s_part[t] + s_part[64 + t] + s_part[128 + t] + s_part[192 + t] + ba3[0];
        s_attn[t] = a;
    }
    __syncthreads();                                // B4

    // ---- ctx partial: ctx[d] += sum_kl attn[kl] * vproj[k,d] ; atomic merge ----
    if (t < 64) {
        float cacc = 0.0f;
#pragma unroll
        for (int g = 0; g < 8; ++g) {
            float vv[8];
#pragma unroll
            for (int u = 0; u < 8; ++u)             // 8 independent gathers in flight
                vv[u] = vproj[s_kvo[g * 8 + u] + t];
#pragma unroll
            for (int u = 0; u < 8; ++u)
                cacc += s_attn[g * 8 + u] * vv[u];
        }
        atomicAdd(&ctx_acc_g[bq * 64 + t], cacc);
    }
}

// ---------------- Kernel 3: LN1 (fused) + gate MLP ; gctx = masked gate*ctx ----------------
__global__ __launch_bounds__(256) void gate_kernel(
    float* __restrict__ ctx,                        // in: raw sums, out: normalized
    const float* __restrict__ ln1_s, const float* __restrict__ ln1_b,
    const float* __restrict__ Wg1, const float* __restrict__ bg1,
    const float* __restrict__ Wg2, const float* __restrict__ bg2,
    const int* __restrict__ valid_lens,
    float* __restrict__ gctx) {
    __shared__ float s_ctx[64];
    __shared__ float s_hg[256];
    const int t  = threadIdx.x;
    const int bq = blockIdx.x;
    const int b  = bq >> 9;
    const int q  = bq & 511;
    if (t < 64) {                                   // wave 0: LN1
        float x = ctx[bq * 64 + t];
        float s = x;
#pragma unroll
        for (int m = 1; m < 64; m <<= 1) s += __shfl_xor(s, m);
        float mu = s * (1.0f / 64.0f);
        float dv = x - mu;
        float vv = dv * dv;
#pragma unroll
        for (int m = 1; m < 64; m <<= 1) vv += __shfl_xor(vv, m);
        float rs = rsqrtf(vv * (1.0f / 64.0f) + LN_EPS);
        float y = dv * rs * ln1_s[t] + ln1_b[t];
        ctx[bq * 64 + t] = y;
        s_ctx[t] = y;
    }
    __syncthreads();
    float a = bg1[t];
#pragma unroll 8
    for (int d = 0; d < 64; ++d) a += s_ctx[d] * Wg1[d * 256 + t];
    s_hg[t] = gelu_tanh(a);
    __syncthreads();
    if (t < 64) {
        float g = bg2[t];
#pragma unroll 8
        for (int jj = 0; jj < 256; ++jj) g += s_hg[jj] * Wg2[jj * 64 + t];
        float val = g * s_ctx[t];
        if (q >= valid_lens[b]) val = -INFINITY;
        gctx[bq * 64 + t] = val;
    }
}

// ---------------- Kernel 4: pooled = max over q ; vnode = LN2(pooled) ----------------
__global__ __launch_bounds__(256) void pool_kernel(
    const float* __restrict__ gctx,
    const float* __restrict__ ln2_s, const float* __restrict__ ln2_b,
    float* __restrict__ vnode_out) {
    __shared__ float s_red[4 * 64];
    const int t = threadIdx.x;
    const int b = blockIdx.x;
    const int d = t & 63;
    const int g = t >> 6;
    float m = -INFINITY;
#pragma unroll 4
    for (int q = g; q < NN; q += 4)
        m = fmaxf(m, gctx[(b * NN + q) * 64 + d]);
    s_red[g * 64 + d] = m;
    __syncthreads();
    if (t < 64) {
        float x = fmaxf(fmaxf(s_red[t], s_red[64 + t]),
                        fmaxf(s_red[128 + t], s_red[192 + t]));
        float s = x;
#pragma unroll
        for (int mm = 1; mm < 64; mm <<= 1) s += __shfl_xor(s, mm);
        float mu = s * (1.0f / 64.0f);
        float dv = x - mu;
        float vv = dv * dv;
#pragma unroll
        for (int mm = 1; mm < 64; mm <<= 1) vv += __shfl_xor(vv, mm);
        float rs = rsqrtf(vv * (1.0f / 64.0f) + LN_EPS);
        vnode_out[b * 64 + t] = dv * rs * ln2_s[t] + ln2_b[t];
    }
}

extern "C" void kernel_launch(void* const* d_in, const int* in_sizes, int n_in,
                              void* d_out, int out_size, void* d_ws, size_t ws_size,
                              hipStream_t stream) {
    const float* qs   = (const float*)d_in[0];
    const float* ks   = (const float*)d_in[1];
    const float* vs   = (const float*)d_in[2];
    const float* qs_s = (const float*)d_in[3];
    const float* ks_s = (const float*)d_in[4];
    const float* qs_t = (const float*)d_in[5];
    const float* ks_t = (const float*)d_in[6];
    const int*   valid_lens = (const int*)d_in[7];
    const float* Wv   = (const float*)d_in[8];
    const float* bv   = (const float*)d_in[9];
    const float* Wa1  = (const float*)d_in[10];
    const float* ba1  = (const float*)d_in[11];
    const float* Wa2  = (const float*)d_in[12];
    const float* ba2  = (const float*)d_in[13];
    const float* Wa3  = (const float*)d_in[14];
    const float* ba3  = (const float*)d_in[15];
    const float* Wg1  = (const float*)d_in[16];
    const float* bg1  = (const float*)d_in[17];
    const float* Wg2  = (const float*)d_in[18];
    const float* bg2  = (const float*)d_in[19];
    const float* ln1_s = (const float*)d_in[20];
    const float* ln1_b = (const float*)d_in[21];
    const float* ln2_s = (const float*)d_in[22];
    const float* ln2_b = (const float*)d_in[23];

    float* out = (float*)d_out;                     // [0,65536): ctx ; [65536,65664): vnode
    float* ws  = (float*)d_ws;
    float* Aq    = ws;                              // B*N*H
    float* Ak    = Aq + BB * NN * HH;               // B*N*H
    float* vproj = Ak + BB * NN * HH;               // B*N*64
    float* gctx  = vproj + BB * NN * 64;            // B*N*64
    unsigned short* Wa2T = (unsigned short*)(gctx + BB * NN * 64);   // 256*256 bf16

    prep_kernel<<<1536, 256, 0, stream>>>(qs, ks, vs, Wa1, ba1, Wv, bv, Wa2,
                                          Aq, Ak, vproj, Wa2T, out);
    attn_ctx_kernel<<<BB * NN * 8, 256, 0, stream>>>(ks_s, qs_s, qs_t, ks_t, valid_lens,
                                                     Wa1, Wa2T, ba2, Wa3, ba3,
                                                     Aq, Ak, vproj, out);
    gate_kernel<<<BB * NN, 256, 0, stream>>>(out, ln1_s, ln1_b, Wg1, bg1, Wg2, bg2,
                                             valid_lens, gctx);
    pool_kernel<<<BB, 256, 0, stream>>>(gctx, ln2_s, ln2_b, out + BB * NN * 64);
}